// Round 7
// baseline (155.644 us; speedup 1.0000x reference)
//
#include <hip/hip_runtime.h>
#include <hip/hip_bf16.h>
#include <cstdint>
#include <cstddef>

#define BATCH 4096
#define INC   1024
#define OUTC  1024
#define NB    8
#define KDIM  (INC * NB)   // 8192 (elements == bytes in i8)

// GEMM tile: 256(M) x 128(N), BK=64 bytes i8, 8 waves (4M x 2N), wave tile 64x64
// (4x4 frags of 16x16x64 i8). Double-buffered LDS, 2 blocks/CU, counted vmcnt(3)
// (T4), setprio (T5), XOR-swizzle (T2), bijective XCD swizzle (T1) -- loop
// byte-identical to R6 (41.2 us, conflicts 0, FETCH compulsory).
// R7 change: EPILOGUE. R0-R6 all shared a 64x scalar-2B-store epilogue (32B
// segments scattered over 4 rows/inst) -- the constant ~15-18 us residual across
// every schedule. Partials now stored PACKED lane-major (8x dwordx4/lane, fully
// coalesced); reduce decodes (p,w,lane,word)->(b,o), dequants, and transposes
// 64x64 tiles through LDS so the final out write is also fully coalesced.
#define BM 256
#define BN 128
#define BKB 64                  // k-bytes per step
#define SPLITS 4
#define KZ (KDIM / SPLITS)      // 2048 bytes per z
#define KSTEPS (KZ / BKB)       // 32 even steps, no tail
#define GRID_BLOCKS ((OUTC / BN) * (BATCH / BM) * SPLITS)   // 8*16*4 = 512 = 2 blocks/CU

// prep dispatch partition: expand | fused rowmax+quant (one block per coeff row)
#define EXPAND_BLOCKS  ((BATCH * INC) / 256)   // 16384
#define QUANT_BLOCKS   OUTC                    // 1024
#define PREP_BLOCKS    (EXPAND_BLOCKS + QUANT_BLOCKS)

typedef int      v4i __attribute__((ext_vector_type(4)));
typedef unsigned v4u __attribute__((ext_vector_type(4)));
typedef char     v8c __attribute__((ext_vector_type(8)));

__device__ __forceinline__ unsigned short f2bf(float f) {
  union { float f; unsigned u; } v; v.f = f;
  unsigned r = v.u + 0x7fffu + ((v.u >> 16) & 1u);  // round-to-nearest-even
  return (unsigned short)(r >> 16);
}
__device__ __forceinline__ float bf2f(unsigned short h) {
  union { unsigned u; float f; } v; v.u = ((unsigned)h) << 16; return v.f;
}

// async 16B global -> LDS (DMA; LDS dest = wave-uniform base + lane*16)
__device__ __forceinline__ void gld16(const char* g, char* l) {
  __builtin_amdgcn_global_load_lds(
      (const __attribute__((address_space(1))) unsigned int*)g,
      (__attribute__((address_space(3))) unsigned int*)l, 16, 0, 0);
}

// ---------------- Phase 1 (fused dispatch): expand basis | rowmax+quantize coeffs -------
__global__ __launch_bounds__(256) void prep_kernel(
    const float* __restrict__ x, const float4* __restrict__ coeffs4,
    const float* __restrict__ centers, const float* __restrict__ slopes,
    const float* __restrict__ alpha, const float* __restrict__ beta,
    char* __restrict__ Ai8, int* __restrict__ Ci8i,
    float* __restrict__ maxrow, int* __restrict__ qcsum) {
  const int blk = blockIdx.x;
  const int tid = threadIdx.x;
  if (blk < EXPAND_BLOCKS) {
    const int idx = blk * 256 + tid;          // (b,i) pair
    const int i = idx & (INC - 1);
    const float u = alpha[i] * x[idx] + beta[i];
    const float s0 = slopes[i * NB];
    const float c0 = centers[i * NB];
    const float c1 = centers[i * NB + 1];
    const float L2E2 = 2.8853900817779268f;   // 2*log2(e)
    const float a2 = L2E2 * s0;
    float e = __builtin_amdgcn_exp2f(a2 * (c0 - u));   // inf -> rcp -> 0: correct limit
    const float R = __builtin_amdgcn_exp2f(a2 * (c1 - c0));
    v8c q;
#pragma unroll
    for (int m = 0; m < 8; ++m) {
      float basis = __builtin_amdgcn_rcpf(1.0f + e);
      q[m] = (char)(int)rintf(basis * 254.0f - 127.0f);
      e *= R;
    }
    *(v8c*)(Ai8 + (size_t)idx * 8) = q;   // 8B coalesced store
  } else {
    const int o = blk - EXPAND_BLOCKS;
    const float4* row = coeffs4 + (size_t)o * (KDIM / 4);
    float4 v[8];
    float m = 0.0f;
#pragma unroll
    for (int j = 0; j < 8; ++j) {
      v[j] = row[tid + 256 * j];
      m = fmaxf(m, fmaxf(fmaxf(fabsf(v[j].x), fabsf(v[j].y)),
                         fmaxf(fabsf(v[j].z), fabsf(v[j].w))));
    }
#pragma unroll
    for (int off = 32; off; off >>= 1) m = fmaxf(m, __shfl_xor(m, off));
    __shared__ float wm[4];
    __shared__ int   wq[4];
    if ((tid & 63) == 0) wm[tid >> 6] = m;
    __syncthreads();
    const float M = fmaxf(fmaxf(fmaxf(wm[0], wm[1]), fmaxf(wm[2], wm[3])), 1e-30f);
    const float s = 127.0f / M;
    int qs = 0;
#pragma unroll
    for (int j = 0; j < 8; ++j) {
      int q0 = (int)rintf(v[j].x * s), q1 = (int)rintf(v[j].y * s);
      int q2 = (int)rintf(v[j].z * s), q3 = (int)rintf(v[j].w * s);
      Ci8i[(size_t)o * (KDIM / 4) + tid + 256 * j] =
          (q0 & 0xFF) | ((q1 & 0xFF) << 8) | ((q2 & 0xFF) << 16) | ((q3 & 0xFF) << 24);
      qs += q0 + q1 + q2 + q3;
    }
#pragma unroll
    for (int off = 32; off; off >>= 1) qs += __shfl_xor(qs, off);
    if ((tid & 63) == 0) wq[tid >> 6] = qs;
    __syncthreads();
    if (tid == 0) { maxrow[o] = M; qcsum[o] = wq[0] + wq[1] + wq[2] + wq[3]; }
  }
}

// ---------------- Phase 2: i8 16x16x64 MFMA GEMM (loop = R6, packed epilogue) -----------
// Packed partials layout (u32 units):
//   word j of lane l, wave w, logical plane-block p, split z lives at
//   W = ((z*128 + p)*8 + w)*2048 + (j>>2)*256 + l*4 + (j&3)
//   where j = fm*8 + fn*2 + rr packs acc[fm][fn][2rr],[2rr+1] as bf16 lo|hi.
// Each chunk (j>>2) is 64 lanes x 16B contiguous = 1 KiB -> perfectly coalesced.
__global__ __launch_bounds__(512, 4) void gemm_kernel(
    const char* __restrict__ A, const char* __restrict__ C,
    unsigned* __restrict__ partials) {
  __shared__ __align__(16) char As[2][BM * BKB];   // 2 x 16 KiB
  __shared__ __align__(16) char Bs[2][BN * BKB];   // 2 x  8 KiB

  // XCD-aware bijective remap: each XCD owns 64 consecutive logical blocks
  const int id = (blockIdx.x & 7) * (GRID_BLOCKS / 8) + (blockIdx.x >> 3);
  const int z  = id >> 7;          // 128 blocks per z-plane
  const int p  = id & 127;
  const int by = p >> 3;           // 16 M-tiles
  const int bx = p & 7;            // 8 N-tiles
  const int bm0 = by * BM;
  const int bn0 = bx * BN;
  const int kt0 = z * KZ;

  const int tid  = threadIdx.x;
  const int wave = tid >> 6;
  const int lane = tid & 63;
  const int quad = lane >> 4;
  const int lm   = lane & 15;
  const int wm   = (wave >> 1) * 64;   // 4 M-wave-groups
  const int wn   = (wave & 1) * 64;    // 2 N-wave-groups

  // staging decode: lane -> slot (row = rb+(lane>>2), gs = lane&3);
  // global group gg = gs ^ ((row>>1)&3)
  const int r4 = lane >> 2;
  const int gg = (lane & 3) ^ ((lane >> 3) & 3);

  const char* pA0 = A + (size_t)(bm0 + wave * 32 + r4) * KDIM + kt0 + gg * 16;
  const char* pB0 = C + (size_t)(bn0 + wave * 16 + r4) * KDIM + kt0 + gg * 16;
  const int loA = wave * 32 * BKB;
  const int loB = wave * 16 * BKB;

  v4i acc[4][4] = {};
  const int kx = (quad ^ ((lm >> 1) & 3)) * 16;   // swizzled ds_read group offset

#define STAGE(SL)                                                            \
  {                                                                          \
    gld16(pA0,                      As[SL] + loA);                           \
    gld16(pA0 + (size_t)16 * KDIM,  As[SL] + loA + 16 * BKB);                \
    gld16(pB0,                      Bs[SL] + loB);                           \
    pA0 += BKB; pB0 += BKB;                                                  \
  }

  STAGE(0);
  STAGE(1);

  for (int t = 0; t < KSTEPS; ++t) {
    const int cur = t & 1;
    if (t < KSTEPS - 1) {
      asm volatile("s_waitcnt vmcnt(3)" ::: "memory");   // batch t landed
    } else {
      asm volatile("s_waitcnt vmcnt(0)" ::: "memory");   // last batch
    }
    __builtin_amdgcn_sched_barrier(0);
    __builtin_amdgcn_s_barrier();

    const char* cA = As[cur];
    const char* cB = Bs[cur];
    v4i a[4], b[4];
#pragma unroll
    for (int f = 0; f < 4; ++f)
      a[f] = *(const v4i*)(cA + (wm + f * 16 + lm) * BKB + kx);
#pragma unroll
    for (int f = 0; f < 4; ++f)
      b[f] = *(const v4i*)(cB + (wn + f * 16 + lm) * BKB + kx);

    __builtin_amdgcn_s_setprio(1);
#pragma unroll
    for (int fm = 0; fm < 4; ++fm)
#pragma unroll
      for (int fn = 0; fn < 4; ++fn)
        acc[fm][fn] = __builtin_amdgcn_mfma_i32_16x16x64_i8(a[fm], b[fn], acc[fm][fn], 0, 0, 0);
    __builtin_amdgcn_s_setprio(0);

    __builtin_amdgcn_s_barrier();        // all waves done reading slot cur
    if (t < KSTEPS - 2) STAGE(cur);      // batch t+2 -> slot t&1 (WAR-safe)
  }
#undef STAGE

  // ---- packed epilogue: 32 bf16-pair words per lane, 8 coalesced dwordx4 stores ----
  unsigned w32[32];
#pragma unroll
  for (int fm = 0; fm < 4; ++fm)
#pragma unroll
    for (int fn = 0; fn < 4; ++fn)
#pragma unroll
      for (int rr = 0; rr < 2; ++rr)
        w32[fm * 8 + fn * 2 + rr] =
            (unsigned)f2bf((float)acc[fm][fn][2 * rr]) |
            ((unsigned)f2bf((float)acc[fm][fn][2 * rr + 1]) << 16);

  unsigned* outp = partials + (((size_t)z * 128 + p) * 8 + wave) * 2048 + lane * 4;
#pragma unroll
  for (int c = 0; c < 8; ++c)
    *(v4u*)(outp + c * 256) = v4u{w32[4 * c], w32[4 * c + 1], w32[4 * c + 2], w32[4 * c + 3]};
}

// ---------------- Phase 3: reduce + dequant + un-pack transpose ----------------
// One block per (p, w) 64x64 output region. Reads the 4 z-copies of the packed
// region coalesced (2x uint4/thread/z), decodes (lane,word)->(b_local,o_local),
// dequants y = M[o]*(S + 127*Q[o])/32258, transposes through LDS, writes out
// [b][o] fully coalesced (16 consecutive floats per thread).
__global__ __launch_bounds__(256) void reduce_kernel(
    const unsigned* __restrict__ P, const float* __restrict__ maxrow,
    const int* __restrict__ qcsum, float* __restrict__ out) {
  const int blk = blockIdx.x;         // 0..1023
  const int p = blk >> 3, w = blk & 7;
  const int bm0 = (p >> 3) * BM, bn0 = (p & 7) * BN;
  const int B0 = bm0 + (w >> 1) * 64;
  const int O0 = bn0 + (w & 1) * 64;
  const int t = threadIdx.x;

  __shared__ float tile[64][65];
  __shared__ float sM[64];
  __shared__ float sQ[64];
  if (t < 64) { sM[t] = maxrow[O0 + t]; sQ[t] = 127.0f * (float)qcsum[O0 + t]; }
  __syncthreads();

  const size_t base = ((size_t)p * 8 + w) * 2048 + (size_t)t * 8;
  const size_t zs   = (size_t)128 * 8 * 2048;   // u32 per z-plane
  float slo[8] = {}, shi[8] = {};
#pragma unroll
  for (int z = 0; z < SPLITS; ++z) {
    v4u ua = *(const v4u*)(P + z * zs + base);
    v4u ub = *(const v4u*)(P + z * zs + base + 4);
#pragma unroll
    for (int k = 0; k < 4; ++k) {
      slo[k]     += bf2f((unsigned short)(ua[k] & 0xFFFFu));
      shi[k]     += bf2f((unsigned short)(ua[k] >> 16));
      slo[k + 4] += bf2f((unsigned short)(ub[k] & 0xFFFFu));
      shi[k + 4] += bf2f((unsigned short)(ub[k] >> 16));
    }
  }
  const float inv = 1.0f / 32258.0f;   // 127*254
#pragma unroll
  for (int k = 0; k < 8; ++k) {
    const int W  = t * 8 + k;          // u32 index within region
    const int c  = W >> 8;             // chunk 0..7
    const int l  = (W >> 2) & 63;      // lane
    const int j  = (c << 2) | (W & 3); // word id = fm*8 + fn*2 + rr
    const int fm = j >> 3, fn = (j >> 1) & 3, rr = j & 1;
    const int bl = fm * 16 + (l >> 4) * 4 + rr * 2;   // b_local (row), pair rows bl, bl+1
    const int ol = fn * 16 + (l & 15);                // o_local (col)
    const float M = sM[ol], corr = sQ[ol];
    tile[bl][ol]     = M * (slo[k] + corr) * inv;
    tile[bl + 1][ol] = M * (shi[k] + corr) * inv;
  }
  __syncthreads();

  const int row = t >> 2;
  const int c0  = (t & 3) * 16;
  float* op = out + (size_t)(B0 + row) * OUTC + O0 + c0;
#pragma unroll
  for (int i = 0; i < 4; ++i) {
    *(float4*)(op + 4 * i) = float4{tile[row][c0 + 4 * i],     tile[row][c0 + 4 * i + 1],
                                    tile[row][c0 + 4 * i + 2], tile[row][c0 + 4 * i + 3]};
  }
}

extern "C" void kernel_launch(void* const* d_in, const int* in_sizes, int n_in,
                              void* d_out, int out_size, void* d_ws, size_t ws_size,
                              hipStream_t stream) {
  const float* x       = (const float*)d_in[0];
  const float* coeffs  = (const float*)d_in[1];
  const float* centers = (const float*)d_in[2];
  const float* slopes  = (const float*)d_in[3];
  const float* alpha   = (const float*)d_in[4];
  const float* beta    = (const float*)d_in[5];
  float* out = (float*)d_out;

  const size_t a_bytes    = (size_t)BATCH * KDIM;                 // 32 MiB i8
  const size_t c_bytes    = (size_t)OUTC * KDIM;                  // 8 MiB i8
  const size_t stat_bytes = OUTC * sizeof(float);                 // 4 KiB
  const size_t qcs_bytes  = OUTC * sizeof(int);                   // 4 KiB
  const size_t part_bytes = (size_t)SPLITS * BATCH * OUTC * 2;    // 32 MiB bf16-pairs
  if (ws_size < a_bytes + c_bytes + stat_bytes + qcs_bytes + part_bytes) return;

  char*  Ai8    = (char*)d_ws;
  char*  Ci8    = Ai8 + a_bytes;
  float* maxrow = (float*)(Ci8 + c_bytes);
  int*   qcsum  = (int*)((char*)maxrow + stat_bytes);
  unsigned* parts = (unsigned*)((char*)qcsum + qcs_bytes);

  prep_kernel<<<PREP_BLOCKS, 256, 0, stream>>>(
      x, (const float4*)coeffs, centers, slopes, alpha, beta,
      Ai8, (int*)Ci8, maxrow, qcsum);

  gemm_kernel<<<GRID_BLOCKS, 512, 0, stream>>>(Ai8, Ci8, parts);

  reduce_kernel<<<128 * 8, 256, 0, stream>>>(parts, maxrow, qcsum, out);
}